// Round 2
// baseline (1940.429 us; speedup 1.0000x reference)
//
#include <hip/hip_runtime.h>

#define SLOPE 0.01f
#define EPSB 1e-5f
#define INV_CNT (1.0f/131072.0f)

typedef unsigned short ushortT;
typedef unsigned int uintT;

__device__ float g_stats[3][2][128];   // [which][sum|sumsq][channel]
__device__ float g_sb[3][2][128];      // [which][scale|bias][channel]

__device__ __forceinline__ float lrelu(float x){ return x > 0.f ? x : SLOPE*x; }
__device__ __forceinline__ ushortT f2b(float f){
  uintT u = __float_as_uint(f);
  uintT r = (u + 0x7fffu + ((u >> 16) & 1u)) >> 16;   // RNE
  return (ushortT)r;
}
__device__ __forceinline__ float b2f(ushortT h){ return __uint_as_float(((uintT)h) << 16); }

// ---------------- K0: zero stats ----------------
__global__ void k_zero(){
  int i = blockIdx.x*256 + threadIdx.x;
  if (i < 768) ((float*)g_stats)[i] = 0.f;
}

// ---------------- K1: conv1 (ci=64 -> co=128, K=3, pad=1), y1 fp32 to d_out, BN1 stats ----------------
__global__ __launch_bounds__(256) void k_conv1(const float* __restrict__ x,
                                               const float* __restrict__ w1,
                                               float* __restrict__ y1){
  __shared__ float xs[32][35];    // [cil][t+1], slots 0 and 33 zero pad
  __shared__ float ws[128][97];   // [co][cil*3+k]
  const int bn = blockIdx.x;
  const int b = bn >> 8, n = bn & 255;
  const int tid = threadIdx.x;
  const int co0 = (tid >> 3) * 4;
  const int t0  = (tid & 7) * 4;
  float acc[4][4];
  #pragma unroll
  for (int j = 0; j < 4; ++j)
    #pragma unroll
    for (int i = 0; i < 4; ++i) acc[j][i] = 0.f;

  for (int cc = 0; cc < 2; ++cc){
    __syncthreads();
    #pragma unroll
    for (int rep = 0; rep < 48; ++rep){
      int e = rep*256 + tid;
      int co = e / 96, r = e - co*96;
      ws[co][r] = w1[co*192 + cc*96 + r];
    }
    {
      int t = tid >> 3;
      int cil0 = (tid & 7) * 4;
      const float* px = x + (((b*32 + t)*256 + n)*64) + cc*32 + cil0;
      float4 v = *(const float4*)px;
      xs[cil0+0][t+1] = v.x; xs[cil0+1][t+1] = v.y;
      xs[cil0+2][t+1] = v.z; xs[cil0+3][t+1] = v.w;
    }
    if (tid < 32){ xs[tid][0] = 0.f; xs[tid][33] = 0.f; }
    __syncthreads();

    for (int cil = 0; cil < 32; ++cil){
      float xv[6];
      #pragma unroll
      for (int u = 0; u < 6; ++u) xv[u] = xs[cil][t0 + u];
      #pragma unroll
      for (int k = 0; k < 3; ++k){
        #pragma unroll
        for (int j = 0; j < 4; ++j){
          float w = ws[co0 + j][cil*3 + k];
          #pragma unroll
          for (int i = 0; i < 4; ++i)
            acc[j][i] = fmaf(w, xv[i + k], acc[j][i]);
        }
      }
    }
  }
  #pragma unroll
  for (int j = 0; j < 4; ++j){
    float s = 0.f, q = 0.f;
    #pragma unroll
    for (int i = 0; i < 4; ++i){ float v = acc[j][i]; s += v; q += v*v; }
    #pragma unroll
    for (int off = 1; off < 8; off <<= 1){
      s += __shfl_xor(s, off, 8);
      q += __shfl_xor(q, off, 8);
    }
    if ((tid & 7) == 0){
      atomicAdd(&g_stats[0][0][co0+j], s);
      atomicAdd(&g_stats[0][1][co0+j], q);
    }
    float4 o4 = make_float4(acc[j][0], acc[j][1], acc[j][2], acc[j][3]);
    *(float4*)(y1 + bn*4096 + (co0+j)*32 + t0) = o4;
  }
}

// ---------------- K2: finalize BN stats -> scale/bias (device globals) ----------------
__global__ void k_finalize(const float* __restrict__ g, const float* __restrict__ bta, int which){
  int c = threadIdx.x;   // 128
  float mean = g_stats[which][0][c] * INV_CNT;
  float var  = g_stats[which][1][c] * INV_CNT - mean*mean;
  float sc = g[c] * rsqrtf(var + EPSB);
  g_sb[which][0][c] = sc;
  g_sb[which][1][c] = bta[c] - mean*sc;
}

// ---------------- K3: conv2 over bn1+relu(y1); stores RAW pre-BN2 output as bf16
//                  directly in spa layout: spa[(b*32+tp)*256+n][cp], off=co*32+t=tp*128+cp ----------------
__global__ __launch_bounds__(256) void k_conv2(const float* __restrict__ y1,
                                               const float* __restrict__ w2,
                                               ushortT* __restrict__ spa){
  __shared__ float xs[32][35];
  __shared__ float ws[128][97];
  const int bn = blockIdx.x;
  const int b = bn >> 8, n = bn & 255;
  const int tid = threadIdx.x;
  const int co0 = (tid >> 3) * 4;
  const int t0  = (tid & 7) * 4;
  float acc[4][4];
  #pragma unroll
  for (int j = 0; j < 4; ++j)
    #pragma unroll
    for (int i = 0; i < 4; ++i) acc[j][i] = 0.f;

  for (int cc = 0; cc < 4; ++cc){
    __syncthreads();
    #pragma unroll
    for (int rep = 0; rep < 48; ++rep){
      int e = rep*256 + tid;
      int co = e / 96, r = e - co*96;
      ws[co][r] = w2[co*384 + cc*96 + r];
    }
    {
      int cil = tid >> 3;
      int tt  = (tid & 7) * 4;
      int ci  = cc*32 + cil;
      float sc = g_sb[0][0][ci], bi = g_sb[0][1][ci];
      float4 v = *(const float4*)(y1 + bn*4096 + ci*32 + tt);
      xs[cil][tt+1] = fmaxf(fmaf(v.x, sc, bi), 0.f);
      xs[cil][tt+2] = fmaxf(fmaf(v.y, sc, bi), 0.f);
      xs[cil][tt+3] = fmaxf(fmaf(v.z, sc, bi), 0.f);
      xs[cil][tt+4] = fmaxf(fmaf(v.w, sc, bi), 0.f);
    }
    if (tid < 32){ xs[tid][0] = 0.f; xs[tid][33] = 0.f; }
    __syncthreads();

    for (int cil = 0; cil < 32; ++cil){
      float xv[6];
      #pragma unroll
      for (int u = 0; u < 6; ++u) xv[u] = xs[cil][t0 + u];
      #pragma unroll
      for (int k = 0; k < 3; ++k){
        #pragma unroll
        for (int j = 0; j < 4; ++j){
          float w = ws[co0 + j][cil*3 + k];
          #pragma unroll
          for (int i = 0; i < 4; ++i)
            acc[j][i] = fmaf(w, xv[i + k], acc[j][i]);
        }
      }
    }
  }
  #pragma unroll
  for (int j = 0; j < 4; ++j){
    float s = 0.f, q = 0.f;
    #pragma unroll
    for (int i = 0; i < 4; ++i){ float v = acc[j][i]; s += v; q += v*v; }
    #pragma unroll
    for (int off = 1; off < 8; off <<= 1){
      s += __shfl_xor(s, off, 8);
      q += __shfl_xor(q, off, 8);
    }
    if ((tid & 7) == 0){
      atomicAdd(&g_stats[1][0][co0+j], s);
      atomicAdd(&g_stats[1][1][co0+j], q);
    }
    // permuted store: off = co*32 + t in [0,4096) -> tp = off>>7, cp = off&127
    int off = (co0 + j)*32 + t0;
    int tp = off >> 7, cp = off & 127;
    int row = (b*32 + tp)*256 + n;
    uintT u0 = (uintT)f2b(acc[j][0]) | ((uintT)f2b(acc[j][1]) << 16);
    uintT u1 = (uintT)f2b(acc[j][2]) | ((uintT)f2b(acc[j][3]) << 16);
    *(uint2*)(spa + row*128 + cp) = make_uint2(u0, u1);
  }
}

// ---------------- K4: in-place BN2 + relu on spa (bf16) ----------------
__global__ void k_act(ushortT* __restrict__ spa){
  int idx = blockIdx.x*256 + threadIdx.x;   // 2M threads, 8 elems each
  int flat = idx*8;
  int cp0 = flat & 127;
  int row = flat >> 7;
  int bpp = row >> 8;
  int tp = bpp & 31;
  int c = (tp*128 + cp0) >> 5;              // same channel for all 8 (cp0 mult of 8)
  float sc = g_sb[1][0][c], bi = g_sb[1][1][c];
  uint4 v = *(uint4*)(spa + flat);
  float f[8];
  f[0]=b2f((ushortT)(v.x&0xffff)); f[1]=b2f((ushortT)(v.x>>16));
  f[2]=b2f((ushortT)(v.y&0xffff)); f[3]=b2f((ushortT)(v.y>>16));
  f[4]=b2f((ushortT)(v.z&0xffff)); f[5]=b2f((ushortT)(v.z>>16));
  f[6]=b2f((ushortT)(v.w&0xffff)); f[7]=b2f((ushortT)(v.w>>16));
  #pragma unroll
  for (int i = 0; i < 8; ++i) f[i] = fmaxf(fmaf(f[i], sc, bi), 0.f);
  v.x = (uintT)f2b(f[0]) | ((uintT)f2b(f[1])<<16);
  v.y = (uintT)f2b(f[2]) | ((uintT)f2b(f[3])<<16);
  v.z = (uintT)f2b(f[4]) | ((uintT)f2b(f[5])<<16);
  v.w = (uintT)f2b(f[6]) | ((uintT)f2b(f[7])<<16);
  *(uint4*)(spa + flat) = v;
}

// ---------------- K5/K8: [rows x 128] @ [128 x 128]^T + bias, A in bf16, out fp32 ----------------
__global__ __launch_bounds__(256) void k_gemm128(const ushortT* __restrict__ A,
                                                 const float* __restrict__ W,
                                                 const float* __restrict__ bvec,
                                                 float* __restrict__ outp,
                                                 int do_stats){
  __shared__ float As[64][65];
  __shared__ float Ws[64][129];
  __shared__ float ssum[128], ssq[128];
  const int rowbase = blockIdx.x * 64;
  const int tid = threadIdx.x;
  const int rg = tid >> 4, eg = tid & 15;
  const int r0 = rg * 4;
  float acc[4][8];
  #pragma unroll
  for (int i = 0; i < 4; ++i)
    #pragma unroll
    for (int j = 0; j < 8; ++j) acc[i][j] = 0.f;
  if (do_stats && tid < 128){ ssum[tid] = 0.f; ssq[tid] = 0.f; }

  for (int dc = 0; dc < 2; ++dc){
    __syncthreads();
    #pragma unroll
    for (int rep = 0; rep < 2; ++rep){          // As: 64 x 64 from bf16
      int flat = rep*2048 + tid*8;
      int r = flat >> 6, c = flat & 63;
      uint4 v = *(const uint4*)(A + (rowbase + r)*128 + dc*64 + c);
      As[r][c+0]=b2f((ushortT)(v.x&0xffff)); As[r][c+1]=b2f((ushortT)(v.x>>16));
      As[r][c+2]=b2f((ushortT)(v.y&0xffff)); As[r][c+3]=b2f((ushortT)(v.y>>16));
      As[r][c+4]=b2f((ushortT)(v.z&0xffff)); As[r][c+5]=b2f((ushortT)(v.z>>16));
      As[r][c+6]=b2f((ushortT)(v.w&0xffff)); As[r][c+7]=b2f((ushortT)(v.w>>16));
    }
    #pragma unroll
    for (int rep = 0; rep < 8; ++rep){          // Ws: 64 d x 128 e
      int flat = rep*1024 + tid*4;
      int e = flat >> 6, dd = flat & 63;
      float4 v = *(const float4*)(W + e*128 + dc*64 + dd);
      Ws[dd][e] = v.x; Ws[dd+1][e] = v.y; Ws[dd+2][e] = v.z; Ws[dd+3][e] = v.w;
    }
    __syncthreads();
    for (int d = 0; d < 64; ++d){
      float av[4], wv[8];
      #pragma unroll
      for (int i = 0; i < 4; ++i) av[i] = As[r0+i][d];
      #pragma unroll
      for (int j = 0; j < 8; ++j) wv[j] = Ws[d][eg + 16*j];
      #pragma unroll
      for (int i = 0; i < 4; ++i)
        #pragma unroll
        for (int j = 0; j < 8; ++j)
          acc[i][j] = fmaf(av[i], wv[j], acc[i][j]);
    }
  }
  float bv[8];
  #pragma unroll
  for (int j = 0; j < 8; ++j) bv[j] = bvec[eg + 16*j];
  #pragma unroll
  for (int j = 0; j < 8; ++j){
    float s = 0.f, q = 0.f;
    #pragma unroll
    for (int i = 0; i < 4; ++i){
      float v = acc[i][j] + bv[j];
      outp[(rowbase + r0 + i)*128 + eg + 16*j] = v;
      s += v; q += v*v;
    }
    if (do_stats){ atomicAdd(&ssum[eg+16*j], s); atomicAdd(&ssq[eg+16*j], q); }
  }
  if (do_stats){
    __syncthreads();
    if (tid < 128){
      atomicAdd(&g_stats[2][0][tid], ssum[tid]);
      atomicAdd(&g_stats[2][1][tid], ssq[tid]);
    }
  }
}

// ---------------- K6: fused adj(softmax(leaky(MM^T-1e8 I)))+I then agg = adj@spa ----------------
// block = (bp, nt): rows nt*64..nt*64+63 of batch bp. agg written bf16.
__global__ __launch_bounds__(256) void k_adjagg(const float* __restrict__ mapped,
                                                const ushortT* __restrict__ spa,
                                                ushortT* __restrict__ agg){
  __shared__ __align__(16) char smem[50688];
  float   (*Ams)[257]  = (float(*)[257])smem;          // 32896 B (phase 1)
  ushortT (*Ps)[264]   = (ushortT(*)[264])smem;        // 33792 B (phase 2, aliases Ams)
  float   (*spas)[132] = (float(*)[132])(smem + 33792);// 16896 B -> 50688 total
  const int bp = blockIdx.x >> 2;
  const int nt = blockIdx.x & 3;
  const int tid = threadIdx.x;
  const int ng = tid >> 4, mg = tid & 15;
  const int n0 = ng * 4;
  float acc[4][16];
  #pragma unroll
  for (int i = 0; i < 4; ++i)
    #pragma unroll
    for (int j = 0; j < 16; ++j) acc[i][j] = 0.f;
  const float* mb = mapped + bp*(256*128);

  // phase 1: S = M_rows @ M^T
  for (int ec = 0; ec < 4; ++ec){
    __syncthreads();
    #pragma unroll
    for (int rep = 0; rep < 8; ++rep){
      int flat = rep*1024 + tid*4;
      int m = flat >> 5, el = flat & 31;
      float4 v = *(const float4*)(mb + m*128 + ec*32 + el);
      Ams[el][m] = v.x; Ams[el+1][m] = v.y; Ams[el+2][m] = v.z; Ams[el+3][m] = v.w;
    }
    __syncthreads();
    for (int e = 0; e < 32; ++e){
      float av[4], bv[16];
      #pragma unroll
      for (int i = 0; i < 4; ++i) av[i] = Ams[e][nt*64 + n0 + i];
      #pragma unroll
      for (int j = 0; j < 16; ++j) bv[j] = Ams[e][mg + 16*j];
      #pragma unroll
      for (int i = 0; i < 4; ++i)
        #pragma unroll
        for (int j = 0; j < 16; ++j)
          acc[i][j] = fmaf(av[i], bv[j], acc[i][j]);
    }
  }
  __syncthreads();   // last Ams read done; safe to alias with Ps

  // softmax rows -> P, store bf16 to LDS
  #pragma unroll
  for (int i = 0; i < 4; ++i){
    int nrow = nt*64 + n0 + i;
    float vv[16];
    float mx = -1e30f;
    #pragma unroll
    for (int j = 0; j < 16; ++j){
      int m = mg + 16*j;
      float v = acc[i][j];
      if (m == nrow) v -= 1e8f;
      v = lrelu(v);
      vv[j] = v;
      mx = fmaxf(mx, v);
    }
    #pragma unroll
    for (int off = 1; off < 16; off <<= 1) mx = fmaxf(mx, __shfl_xor(mx, off, 16));
    float sum = 0.f;
    #pragma unroll
    for (int j = 0; j < 16; ++j){ float e = __expf(vv[j] - mx); vv[j] = e; sum += e; }
    #pragma unroll
    for (int off = 1; off < 16; off <<= 1) sum += __shfl_xor(sum, off, 16);
    float inv = 1.0f / sum;
    #pragma unroll
    for (int j = 0; j < 16; ++j)
      Ps[n0 + i][mg + 16*j] = f2b(vv[j] * inv);
  }

  // phase 2: agg_rows = P @ spa_bp  (+ spa_row for the +I)
  float acc2[4][8];
  #pragma unroll
  for (int i = 0; i < 4; ++i)
    #pragma unroll
    for (int j = 0; j < 8; ++j) acc2[i][j] = 0.f;

  for (int mc = 0; mc < 8; ++mc){
    __syncthreads();
    #pragma unroll
    for (int rep = 0; rep < 2; ++rep){        // stage 32 x 128 spa tile (bf16 -> fp32)
      int flat = rep*2048 + tid*8;
      int m = flat >> 7, dd = flat & 127;
      uint4 v = *(const uint4*)(spa + (bp*256 + mc*32 + m)*128 + dd);
      spas[m][dd+0]=b2f((ushortT)(v.x&0xffff)); spas[m][dd+1]=b2f((ushortT)(v.x>>16));
      spas[m][dd+2]=b2f((ushortT)(v.y&0xffff)); spas[m][dd+3]=b2f((ushortT)(v.y>>16));
      spas[m][dd+4]=b2f((ushortT)(v.z&0xffff)); spas[m][dd+5]=b2f((ushortT)(v.z>>16));
      spas[m][dd+6]=b2f((ushortT)(v.w&0xffff)); spas[m][dd+7]=b2f((ushortT)(v.w>>16));
    }
    __syncthreads();
    for (int ml = 0; ml < 32; ++ml){
      float av[4], sv[8];
      #pragma unroll
      for (int i = 0; i < 4; ++i) av[i] = b2f(Ps[n0+i][mc*32 + ml]);
      #pragma unroll
      for (int j = 0; j < 8; ++j) sv[j] = spas[ml][mg + 16*j];
      #pragma unroll
      for (int i = 0; i < 4; ++i)
        #pragma unroll
        for (int j = 0; j < 8; ++j)
          acc2[i][j] = fmaf(av[i], sv[j], acc2[i][j]);
    }
  }
  #pragma unroll
  for (int i = 0; i < 4; ++i){
    int grow = bp*256 + nt*64 + n0 + i;
    #pragma unroll
    for (int j = 0; j < 8; ++j){
      int d = mg + 16*j;
      float v = acc2[i][j] + b2f(spa[grow*128 + d]);   // +I term
      agg[grow*128 + d] = f2b(v);
    }
  }
}

// ---------------- K9: final BN + leaky, in place on d_out ----------------
__global__ void k_bnout(float* __restrict__ outp){
  int idx = blockIdx.x*256 + threadIdx.x;
  int flat = idx*4;
  int o = flat & 127;
  float4 v = *(const float4*)(outp + flat);
  v.x = lrelu(fmaf(v.x, g_sb[2][0][o+0], g_sb[2][1][o+0]));
  v.y = lrelu(fmaf(v.y, g_sb[2][0][o+1], g_sb[2][1][o+1]));
  v.z = lrelu(fmaf(v.z, g_sb[2][0][o+2], g_sb[2][1][o+2]));
  v.w = lrelu(fmaf(v.w, g_sb[2][0][o+3], g_sb[2][1][o+3]));
  *(float4*)(outp + flat) = v;
}

extern "C" void kernel_launch(void* const* d_in, const int* in_sizes, int n_in,
                              void* d_out, int out_size, void* d_ws, size_t ws_size,
                              hipStream_t stream) {
  const float* x    = (const float*)d_in[0];
  const float* w1   = (const float*)d_in[1];
  const float* bn1g = (const float*)d_in[2];
  const float* bn1b = (const float*)d_in[3];
  const float* w2   = (const float*)d_in[4];
  const float* bn2g = (const float*)d_in[5];
  const float* bn2b = (const float*)d_in[6];
  const float* mapw = (const float*)d_in[7];
  const float* mapb = (const float*)d_in[8];
  const float* thw  = (const float*)d_in[9];
  const float* thb  = (const float*)d_in[10];
  const float* bnSg = (const float*)d_in[11];
  const float* bnSb = (const float*)d_in[12];
  float* outp = (float*)d_out;

  // ws: exactly 64 MB -> spa (16M bf16) + agg (16M bf16)
  ushortT* spa = (ushortT*)d_ws;
  ushortT* agg = spa + 16777216;

  // d_out scratch phases: y1 (fp32) -> mapped (fp32) -> out_pre (fp32)
  float* y1     = outp;
  float* mapped = outp;

  k_zero<<<3, 256, 0, stream>>>();
  k_conv1<<<4096, 256, 0, stream>>>(x, w1, y1);
  k_finalize<<<1, 128, 0, stream>>>(bn1g, bn1b, 0);
  k_conv2<<<4096, 256, 0, stream>>>(y1, w2, spa);
  k_finalize<<<1, 128, 0, stream>>>(bn2g, bn2b, 1);
  k_act<<<8192, 256, 0, stream>>>(spa);
  k_gemm128<<<2048, 256, 0, stream>>>(spa, mapw, mapb, mapped, 0);
  k_adjagg<<<2048, 256, 0, stream>>>(mapped, spa, agg);
  k_gemm128<<<2048, 256, 0, stream>>>(agg, thw, thb, outp, 1);
  k_finalize<<<1, 128, 0, stream>>>(bnSg, bnSb, 2);
  k_bnout<<<16384, 256, 0, stream>>>(outp);
}

// Round 5
// 1229.740 us; speedup vs baseline: 1.5779x; 1.5779x over previous
//
#include <hip/hip_runtime.h>

#define SLOPE 0.01f
#define EPSB 1e-5f
#define INV_CNT (1.0f/131072.0f)

typedef unsigned short u16;
typedef unsigned int u32;
typedef __attribute__((ext_vector_type(8))) short s16x8;
typedef __attribute__((ext_vector_type(4))) float f4;

__device__ float g_stats[3][2][128];   // [which][sum|sq][channel]
__device__ float g_sb[3][2][128];      // [which][scale|bias][channel]
__device__ u16 g_w1h[3][128][64];      // [k][co][ci] hi
__device__ u16 g_w1l[3][128][64];      // lo
__device__ u16 g_w2h[3][128][128];
__device__ u16 g_w2l[3][128][128];
__device__ u16 g_wmh[128][128];        // [e][d]
__device__ u16 g_wml[128][128];
__device__ u16 g_wqh[128][128];        // theta
__device__ u16 g_wql[128][128];

__device__ __forceinline__ float lrelu(float x){ return x > 0.f ? x : SLOPE*x; }
__device__ __forceinline__ u16 f2b(float f){
  u32 u = __float_as_uint(f);
  return (u16)((u + 0x7fffu + ((u >> 16) & 1u)) >> 16);   // RNE
}
__device__ __forceinline__ float b2f(u16 h){ return __uint_as_float(((u32)h) << 16); }
__device__ __forceinline__ u32 pk(float a, float b){ return (u32)f2b(a) | ((u32)f2b(b) << 16); }
// split f into hi/lo bf16 pair packed in one u32 (hi in low16, lo in high16)
__device__ __forceinline__ u32 pkhl(float f){
  u16 h = f2b(f);
  u16 l = f2b(f - b2f(h));
  return (u32)h | ((u32)l << 16);
}
__device__ __forceinline__ float unhl(u32 v){ return b2f((u16)(v & 0xffff)) + b2f((u16)(v >> 16)); }

// ---------------- zero stats ----------------
__global__ void k_zero(){
  int i = blockIdx.x*256 + threadIdx.x;
  if (i < 768) ((float*)g_stats)[i] = 0.f;
}

// ---------------- prep: fp32 weights -> bf16 hi/lo device globals ----------------
__global__ void k_prepw(const float* __restrict__ w1, const float* __restrict__ w2,
                        const float* __restrict__ mapw, const float* __restrict__ thw){
  int idx = blockIdx.x*256 + threadIdx.x;
  if (idx < 24576){
    int kk = idx >> 13, r = idx & 8191, co = r >> 6, ci = r & 63;
    float v = w1[co*192 + ci*3 + kk];
    u16 h = f2b(v);
    g_w1h[kk][co][ci] = h; g_w1l[kk][co][ci] = f2b(v - b2f(h));
  } else if (idx < 73728){
    int j = idx - 24576;
    int kk = j >> 14, r = j & 16383, co = r >> 7, ci = r & 127;
    float v = w2[co*384 + ci*3 + kk];
    u16 h = f2b(v);
    g_w2h[kk][co][ci] = h; g_w2l[kk][co][ci] = f2b(v - b2f(h));
  } else if (idx < 90112){
    int j = idx - 73728;
    float v = mapw[j];
    u16 h = f2b(v);
    ((u16*)g_wmh)[j] = h; ((u16*)g_wml)[j] = f2b(v - b2f(h));
  } else if (idx < 106496){
    int j = idx - 90112;
    float v = thw[j];
    u16 h = f2b(v);
    ((u16*)g_wqh)[j] = h; ((u16*)g_wql)[j] = f2b(v - b2f(h));
  }
}

// ---------------- finalize BN stats -> scale/bias ----------------
__global__ void k_finalize(const float* __restrict__ g, const float* __restrict__ bta, int which){
  int c = threadIdx.x;   // 128
  float mean = g_stats[which][0][c] * INV_CNT;
  float var  = g_stats[which][1][c] * INV_CNT - mean*mean;
  float sc = g[c] * rsqrtf(var + EPSB);
  g_sb[which][0][c] = sc;
  g_sb[which][1][c] = bta[c] - mean*sc;
}

// ---------------- conv1 MFMA: x[b,t,n,64] -> y1hl[bn][t][co][h|l] pairs, BN1 stats ----------------
// M=co (8 tiles), N=(nn,t) (4 tiles); wave: 2 co-tiles x 4 n-tiles. K=(kk,ci)=192.
// x staged hi/lo; weights two-pass hi/lo: acc = Hw*Hx + Hw*Lx + Lw*Hx.
__global__ __launch_bounds__(256) void k_conv1(const float* __restrict__ x, u16* __restrict__ y1hl){
  __shared__ __align__(16) u16 a0h[2][34][72];
  __shared__ __align__(16) u16 a0l[2][34][72];
  __shared__ __align__(16) u16 w1s[128][72];
  const int bn0 = blockIdx.x*2;
  const int b = bn0 >> 8, n = bn0 & 255;
  const int tid = threadIdx.x;
  const int w = tid >> 6, l = tid & 63, quad = l >> 4, lm = l & 15;
  f4 acc[2][4];
  #pragma unroll
  for (int i = 0; i < 2; ++i)
    #pragma unroll
    for (int j = 0; j < 4; ++j) acc[i][j] = (f4)0.f;

  { // stage x -> a0h/a0l (hi/lo bf16), transposed to [t][ci]
    int nn = tid >> 7, rem = tid & 127, t = rem >> 2, ci0 = (rem & 3)*16;
    const float* px = x + ((b*32 + t)*256 + n + nn)*64 + ci0;
    u16 hh[16], ll[16];
    #pragma unroll
    for (int j = 0; j < 4; ++j){
      float4 v = *(const float4*)(px + 4*j);
      float vv[4] = {v.x, v.y, v.z, v.w};
      #pragma unroll
      for (int e = 0; e < 4; ++e){
        u16 h = f2b(vv[e]);
        hh[4*j+e] = h; ll[4*j+e] = f2b(vv[e] - b2f(h));
      }
    }
    *(uint4*)&a0h[nn][t+1][ci0]   = *(uint4*)&hh[0];
    *(uint4*)&a0h[nn][t+1][ci0+8] = *(uint4*)&hh[8];
    *(uint4*)&a0l[nn][t+1][ci0]   = *(uint4*)&ll[0];
    *(uint4*)&a0l[nn][t+1][ci0+8] = *(uint4*)&ll[8];
  }
  // zero pad rows t=0,33 (both nn, both arrays): 4 rows x 36 u32 x 2 arrays = 288
  for (int u = tid; u < 288; u += 256){
    int a = u / 144, rr = u % 144, r = rr / 36, cw = rr % 36;
    u32* base = a ? (u32*)&a0l[r>>1][(r&1)*33][0] : (u32*)&a0h[r>>1][(r&1)*33][0];
    base[cw] = 0u;
  }

  for (int kk = 0; kk < 3; ++kk){
    // pass 0: hi weights, terms Hw*Hx + Hw*Lx
    __syncthreads();
    { int co = tid >> 1, c0 = (tid & 1)*32;
      #pragma unroll
      for (int j = 0; j < 4; ++j)
        *(uint4*)&w1s[co][c0 + 8*j] = *(const uint4*)&g_w1h[kk][co][c0 + 8*j];
    }
    __syncthreads();
    #pragma unroll
    for (int s = 0; s < 2; ++s){
      int ci0 = s*32 + quad*8;
      s16x8 af[2], bh[4], bl[4];
      #pragma unroll
      for (int i = 0; i < 2; ++i) af[i] = *(s16x8*)&w1s[(2*w+i)*16 + lm][ci0];
      #pragma unroll
      for (int nt = 0; nt < 4; ++nt){
        bh[nt] = *(s16x8*)&a0h[nt>>1][(nt&1)*16 + lm + kk][ci0];
        bl[nt] = *(s16x8*)&a0l[nt>>1][(nt&1)*16 + lm + kk][ci0];
      }
      #pragma unroll
      for (int i = 0; i < 2; ++i)
        #pragma unroll
        for (int nt = 0; nt < 4; ++nt){
          acc[i][nt] = __builtin_amdgcn_mfma_f32_16x16x32_bf16(af[i], bh[nt], acc[i][nt], 0, 0, 0);
          acc[i][nt] = __builtin_amdgcn_mfma_f32_16x16x32_bf16(af[i], bl[nt], acc[i][nt], 0, 0, 0);
        }
    }
    // pass 1: lo weights, term Lw*Hx
    __syncthreads();
    { int co = tid >> 1, c0 = (tid & 1)*32;
      #pragma unroll
      for (int j = 0; j < 4; ++j)
        *(uint4*)&w1s[co][c0 + 8*j] = *(const uint4*)&g_w1l[kk][co][c0 + 8*j];
    }
    __syncthreads();
    #pragma unroll
    for (int s = 0; s < 2; ++s){
      int ci0 = s*32 + quad*8;
      s16x8 af[2], bh[4];
      #pragma unroll
      for (int i = 0; i < 2; ++i) af[i] = *(s16x8*)&w1s[(2*w+i)*16 + lm][ci0];
      #pragma unroll
      for (int nt = 0; nt < 4; ++nt) bh[nt] = *(s16x8*)&a0h[nt>>1][(nt&1)*16 + lm + kk][ci0];
      #pragma unroll
      for (int i = 0; i < 2; ++i)
        #pragma unroll
        for (int nt = 0; nt < 4; ++nt)
          acc[i][nt] = __builtin_amdgcn_mfma_f32_16x16x32_bf16(af[i], bh[nt], acc[i][nt], 0, 0, 0);
    }
  }
  // epilogue: D row=co(quad*4+reg), col=t(lm). Store 4 (hi,lo) pairs = uint4.
  #pragma unroll
  for (int i = 0; i < 2; ++i){
    int co0 = (2*w+i)*16 + quad*4;
    float s0=0,s1=0,s2=0,s3=0,q0=0,q1=0,q2=0,q3=0;
    #pragma unroll
    for (int nt = 0; nt < 4; ++nt){
      f4 a = acc[i][nt];
      int nn = nt >> 1, t = (nt & 1)*16 + lm;
      uint4 p;
      p.x = pkhl(a.x); p.y = pkhl(a.y); p.z = pkhl(a.z); p.w = pkhl(a.w);
      *(uint4*)&y1hl[(((bn0+nn)*32 + t)*128 + co0)*2] = p;
      s0+=a.x; s1+=a.y; s2+=a.z; s3+=a.w;
      q0+=a.x*a.x; q1+=a.y*a.y; q2+=a.z*a.z; q3+=a.w*a.w;
    }
    #pragma unroll
    for (int m = 1; m < 16; m <<= 1){
      s0+=__shfl_xor(s0,m); s1+=__shfl_xor(s1,m); s2+=__shfl_xor(s2,m); s3+=__shfl_xor(s3,m);
      q0+=__shfl_xor(q0,m); q1+=__shfl_xor(q1,m); q2+=__shfl_xor(q2,m); q3+=__shfl_xor(q3,m);
    }
    if (lm == 0){
      atomicAdd(&g_stats[0][0][co0+0],s0); atomicAdd(&g_stats[0][1][co0+0],q0);
      atomicAdd(&g_stats[0][0][co0+1],s1); atomicAdd(&g_stats[0][1][co0+1],q1);
      atomicAdd(&g_stats[0][0][co0+2],s2); atomicAdd(&g_stats[0][1][co0+2],q2);
      atomicAdd(&g_stats[0][0][co0+3],s3); atomicAdd(&g_stats[0][1][co0+3],q3);
    }
  }
}

// ---------------- conv2 MFMA: bn1+relu(exact y1) -> spa (permuted, bf16, pre-BN2), BN2 stats ----------------
// M=(nn,t) (4 tiles), N=co (8 tiles); wave: 4 m-tiles x 2 co-tiles. K=(kk,ci)=384.
// a1s single bf16 (activated); weights two-pass hi/lo.
__global__ __launch_bounds__(256) void k_conv2(const u16* __restrict__ y1hl, u16* __restrict__ spa){
  __shared__ __align__(16) u16 a1s[2][34][136];
  __shared__ __align__(16) u16 w2s[128][136];
  const int bn0 = blockIdx.x*2;
  const int b = bn0 >> 8, n = bn0 & 255;
  const int tid = threadIdx.x;
  const int w = tid >> 6, l = tid & 63, quad = l >> 4, lm = l & 15;
  f4 acc2[4][2];
  #pragma unroll
  for (int mt = 0; mt < 4; ++mt)
    #pragma unroll
    for (int i = 0; i < 2; ++i) acc2[mt][i] = (f4)0.f;

  { // stage bn1+relu(exact y1) -> a1s
    int nn = tid >> 7, rem = tid & 127, t = rem >> 2, ci0 = (rem & 3)*32;
    const u16* py = y1hl + (((bn0+nn)*32 + t)*128)*2;
    #pragma unroll
    for (int j = 0; j < 4; ++j){
      uint4 va = *(const uint4*)&py[(ci0 + 8*j)*2];       // ci0+8j .. +3 (pairs)
      uint4 vb = *(const uint4*)&py[(ci0 + 8*j + 4)*2];   // +4 .. +7
      u32 vv[8] = {va.x, va.y, va.z, va.w, vb.x, vb.y, vb.z, vb.w};
      u16 oo[8];
      #pragma unroll
      for (int e = 0; e < 8; ++e){
        int ci = ci0 + 8*j + e;
        float f = fmaxf(fmaf(unhl(vv[e]), g_sb[0][0][ci], g_sb[0][1][ci]), 0.f);
        oo[e] = f2b(f);
      }
      *(uint4*)&a1s[nn][t+1][ci0 + 8*j] = *(uint4*)&oo[0];
    }
  }
  // pad rows: 136 u16 = 68 u32 per row, 4 rows
  for (int u = tid; u < 272; u += 256){
    int r = u/68, cw = u%68;
    ((u32*)&a1s[r>>1][(r&1)*33][0])[cw] = 0u;
  }

  for (int kk = 0; kk < 3; ++kk){
    #pragma unroll
    for (int pass = 0; pass < 2; ++pass){
      __syncthreads();
      { int co = tid >> 1, c0 = (tid & 1)*64;
        const u16* src = pass ? &g_w2l[kk][co][0] : &g_w2h[kk][co][0];
        #pragma unroll
        for (int j = 0; j < 8; ++j)
          *(uint4*)&w2s[co][c0 + 8*j] = *(const uint4*)&src[c0 + 8*j];
      }
      __syncthreads();
      #pragma unroll
      for (int s = 0; s < 4; ++s){
        int ci0 = s*32 + quad*8;
        s16x8 ax[4], bw[2];
        #pragma unroll
        for (int mt = 0; mt < 4; ++mt) ax[mt] = *(s16x8*)&a1s[mt>>1][(mt&1)*16 + lm + kk][ci0];
        #pragma unroll
        for (int i = 0; i < 2; ++i) bw[i] = *(s16x8*)&w2s[(2*w+i)*16 + lm][ci0];
        #pragma unroll
        for (int mt = 0; mt < 4; ++mt)
          #pragma unroll
          for (int i = 0; i < 2; ++i)
            acc2[mt][i] = __builtin_amdgcn_mfma_f32_16x16x32_bf16(ax[mt], bw[i], acc2[mt][i], 0, 0, 0);
      }
    }
  }
  // epilogue: D row=t(quad*4+reg), col=co(lm); permuted spa store, stats
  #pragma unroll
  for (int i = 0; i < 2; ++i){
    int co = (2*w+i)*16 + lm;
    float s = 0.f, q = 0.f;
    #pragma unroll
    for (int mt = 0; mt < 4; ++mt){
      f4 a = acc2[mt][i];
      int off0 = co*32 + (mt&1)*16 + quad*4;       // off = co*32 + t
      int tp = off0 >> 7, cp = off0 & 127;
      int row = (b*32 + tp)*256 + (n + (mt>>1));
      uint2 p; p.x = pk(a.x, a.y); p.y = pk(a.z, a.w);
      *(uint2*)&spa[row*128 + cp] = p;
      s += a.x + a.y + a.z + a.w;
      q += a.x*a.x + a.y*a.y + a.z*a.z + a.w*a.w;
    }
    s += __shfl_xor(s, 16); s += __shfl_xor(s, 32);
    q += __shfl_xor(q, 16); q += __shfl_xor(q, 32);
    if (l < 16){
      atomicAdd(&g_stats[1][0][co], s);
      atomicAdd(&g_stats[1][1][co], q);
    }
  }
}

// ---------------- in-place BN2 + relu on spa ----------------
__global__ void k_act(u16* __restrict__ spa){
  int idx = blockIdx.x*256 + threadIdx.x;
  int flat = idx*8;
  int cp0 = flat & 127;
  int row = flat >> 7;
  int bpp = row >> 8;
  int tp = bpp & 31;
  int c = (tp*128 + cp0) >> 5;
  float sc = g_sb[1][0][c], bi = g_sb[1][1][c];
  uint4 v = *(uint4*)(spa + flat);
  u16 h[8]; *(uint4*)&h[0] = v;
  u16 o[8];
  #pragma unroll
  for (int i = 0; i < 8; ++i) o[i] = f2b(fmaxf(fmaf(b2f(h[i]), sc, bi), 0.f));
  *(uint4*)(spa + flat) = *(uint4*)&o[0];
}

// ---------------- gemm128 MFMA: out[r][e] = sum_d A[r][d]*W[e][d] + b[e], W two-pass hi/lo ----------------
// M=e (8 tiles), N=rows (4 tiles); wave: 2 e-tiles x 4 row-tiles. K=128.
__global__ __launch_bounds__(256) void k_gemm128b(const u16* __restrict__ A,
                                                  const float* __restrict__ bvec,
                                                  float* __restrict__ outp,
                                                  int wsel, int do_stats){
  __shared__ __align__(16) u16 As[64][136];
  __shared__ __align__(16) u16 Ws[128][136];
  const u16* Wh = wsel ? &g_wqh[0][0] : &g_wmh[0][0];
  const u16* Wl = wsel ? &g_wql[0][0] : &g_wml[0][0];
  const int rowbase = blockIdx.x * 64;
  const int tid = threadIdx.x;
  const int w = tid >> 6, l = tid & 63, quad = l >> 4, lm = l & 15;
  f4 acc[2][4];
  #pragma unroll
  for (int i = 0; i < 2; ++i)
    #pragma unroll
    for (int rt = 0; rt < 4; ++rt) acc[i][rt] = (f4)0.f;

  { int r = tid >> 2, c0 = (tid & 3)*32;
    #pragma unroll
    for (int j = 0; j < 4; ++j)
      *(uint4*)&As[r][c0 + 8*j] = *(const uint4*)&A[(rowbase + r)*128 + c0 + 8*j];
  }
  #pragma unroll
  for (int pass = 0; pass < 2; ++pass){
    if (pass) __syncthreads();
    { int e = tid >> 1, c0 = (tid & 1)*64;
      const u16* src = (pass ? Wl : Wh) + e*128;
      #pragma unroll
      for (int j = 0; j < 8; ++j)
        *(uint4*)&Ws[e][c0 + 8*j] = *(const uint4*)&src[c0 + 8*j];
    }
    __syncthreads();
    #pragma unroll
    for (int s = 0; s < 4; ++s){
      int k0 = s*32 + quad*8;
      s16x8 aw[2], ba[4];
      #pragma unroll
      for (int i = 0; i < 2; ++i) aw[i] = *(s16x8*)&Ws[(2*w+i)*16 + lm][k0];
      #pragma unroll
      for (int rt = 0; rt < 4; ++rt) ba[rt] = *(s16x8*)&As[rt*16 + lm][k0];
      #pragma unroll
      for (int i = 0; i < 2; ++i)
        #pragma unroll
        for (int rt = 0; rt < 4; ++rt)
          acc[i][rt] = __builtin_amdgcn_mfma_f32_16x16x32_bf16(aw[i], ba[rt], acc[i][rt], 0, 0, 0);
    }
    if (!pass) __syncthreads();   // all reads done before Ws restage
  }
  // epilogue: D row=e(quad*4+reg), col=row(lm) -> float4 stores along e
  #pragma unroll
  for (int i = 0; i < 2; ++i){
    int e0 = (2*w+i)*16 + quad*4;
    f4 bv = *(const f4*)&bvec[e0];
    f4 sv = (f4)0.f, qv = (f4)0.f;
    #pragma unroll
    for (int rt = 0; rt < 4; ++rt){
      int row = rowbase + rt*16 + lm;
      f4 o = acc[i][rt] + bv;
      *(f4*)&outp[row*128 + e0] = o;
      sv += o; qv += o*o;
    }
    if (do_stats){
      #pragma unroll
      for (int m = 1; m < 16; m <<= 1){
        sv.x+=__shfl_xor(sv.x,m); sv.y+=__shfl_xor(sv.y,m); sv.z+=__shfl_xor(sv.z,m); sv.w+=__shfl_xor(sv.w,m);
        qv.x+=__shfl_xor(qv.x,m); qv.y+=__shfl_xor(qv.y,m); qv.z+=__shfl_xor(qv.z,m); qv.w+=__shfl_xor(qv.w,m);
      }
      if (lm == 0){
        atomicAdd(&g_stats[2][0][e0+0],sv.x); atomicAdd(&g_stats[2][1][e0+0],qv.x);
        atomicAdd(&g_stats[2][0][e0+1],sv.y); atomicAdd(&g_stats[2][1][e0+1],qv.y);
        atomicAdd(&g_stats[2][0][e0+2],sv.z); atomicAdd(&g_stats[2][1][e0+2],qv.z);
        atomicAdd(&g_stats[2][0][e0+3],sv.w); atomicAdd(&g_stats[2][1][e0+3],qv.w);
      }
    }
  }
}

// ---------------- fused adj+agg MFMA, mapped staged hi/lo ----------------
// smem aliasing: phase1 mbuf_h(0..20479) + mbuf_l(20480..40959); after barrier:
// Ps(0..33791) + spasT(33792..44031).
__global__ __launch_bounds__(256) void k_adjagg(const float* __restrict__ mapped,
                                                const u16* __restrict__ spa,
                                                u16* __restrict__ agg){
  __shared__ __align__(16) char smem[44032];
  u16 (*mbh)[40]   = (u16(*)[40])(smem);
  u16 (*mbl)[40]   = (u16(*)[40])(smem + 20480);
  u16 (*Ps)[264]   = (u16(*)[264])(smem);
  u16 (*spasT)[40] = (u16(*)[40])(smem + 33792);
  const int bp = blockIdx.x >> 2;
  const int nt = blockIdx.x & 3;
  const int tid = threadIdx.x;
  const int w = tid >> 6, l = tid & 63, quad = l >> 4, lm = l & 15;

  // ---- phase 1: S rows (wave w -> row-tile w) x all 256 cols, hi/lo 3-term ----
  f4 sacc[16];
  #pragma unroll
  for (int ct = 0; ct < 16; ++ct) sacc[ct] = (f4)0.f;

  for (int dc = 0; dc < 4; ++dc){
    __syncthreads();
    { int m = tid;
      const float* pm = mapped + (bp*256 + m)*128 + dc*32;
      u16 hh[32], ll[32];
      #pragma unroll
      for (int j = 0; j < 8; ++j){
        float4 v = *(const float4*)(pm + 4*j);
        float vv[4] = {v.x, v.y, v.z, v.w};
        #pragma unroll
        for (int e = 0; e < 4; ++e){
          u16 h = f2b(vv[e]);
          hh[4*j+e] = h; ll[4*j+e] = f2b(vv[e] - b2f(h));
        }
      }
      #pragma unroll
      for (int j = 0; j < 4; ++j){
        *(uint4*)&mbh[m][8*j] = *(uint4*)&hh[8*j];
        *(uint4*)&mbl[m][8*j] = *(uint4*)&ll[8*j];
      }
    }
    __syncthreads();
    s16x8 amh = *(s16x8*)&mbh[nt*64 + w*16 + lm][quad*8];
    s16x8 aml = *(s16x8*)&mbl[nt*64 + w*16 + lm][quad*8];
    #pragma unroll
    for (int ct = 0; ct < 16; ++ct){
      s16x8 bmh = *(s16x8*)&mbh[ct*16 + lm][quad*8];
      s16x8 bml = *(s16x8*)&mbl[ct*16 + lm][quad*8];
      sacc[ct] = __builtin_amdgcn_mfma_f32_16x16x32_bf16(amh, bmh, sacc[ct], 0, 0, 0);
      sacc[ct] = __builtin_amdgcn_mfma_f32_16x16x32_bf16(amh, bml, sacc[ct], 0, 0, 0);
      sacc[ct] = __builtin_amdgcn_mfma_f32_16x16x32_bf16(aml, bmh, sacc[ct], 0, 0, 0);
    }
  }
  __syncthreads();   // all mbuf reads done; Ps may now overlay

  // ---- softmax (regs only) -> Ps[row][m] bf16 ----
  #pragma unroll
  for (int r = 0; r < 4; ++r){
    int rowg = nt*64 + w*16 + quad*4 + r;
    float v[16]; float mx = -3.0e38f;
    #pragma unroll
    for (int ct = 0; ct < 16; ++ct){
      float t = sacc[ct][r];
      if (ct*16 + lm == rowg) t -= 1e8f;
      t = lrelu(t);
      v[ct] = t; mx = fmaxf(mx, t);
    }
    #pragma unroll
    for (int m = 1; m < 16; m <<= 1) mx = fmaxf(mx, __shfl_xor(mx, m));
    float sum = 0.f;
    #pragma unroll
    for (int ct = 0; ct < 16; ++ct){ float e = __expf(v[ct] - mx); v[ct] = e; sum += e; }
    #pragma unroll
    for (int m = 1; m < 16; m <<= 1) sum += __shfl_xor(sum, m);
    float inv = 1.0f / sum;
    #pragma unroll
    for (int ct = 0; ct < 16; ++ct)
      Ps[w*16 + quad*4 + r][ct*16 + lm] = f2b(v[ct] * inv);
  }

  // ---- phase 2: agg = P @ spa (+ spa for +I). M=d (2 d-tiles/wave), N=rows (4 tiles). ----
  f4 acc2[2][4];
  #pragma unroll
  for (int i = 0; i < 2; ++i)
    #pragma unroll
    for (int rt = 0; rt < 4; ++rt) acc2[i][rt] = (f4)0.f;

  for (int mc = 0; mc < 8; ++mc){
    __syncthreads();
    { int ml = tid >> 3, d0 = (tid & 7)*16;     // transpose-stage spa chunk
      const u16* ps = spa + (bp*256 + mc*32 + ml)*128 + d0;
      u16 h[16];
      *(uint4*)&h[0] = *(const uint4*)ps;
      *(uint4*)&h[8] = *(const uint4*)(ps + 8);
      #pragma unroll
      for (int j = 0; j < 16; ++j) spasT[d0 + j][ml] = h[j];
    }
    __syncthreads();
    s16x8 afs[2], bfp[4];
    #pragma unroll
    for (int i = 0; i < 2; ++i) afs[i] = *(s16x8*)&spasT[(2*w+i)*16 + lm][quad*8];
    #pragma unroll
    for (int rt = 0; rt < 4; ++rt) bfp[rt] = *(s16x8*)&Ps[rt*16 + lm][mc*32 + quad*8];
    #pragma unroll
    for (int i = 0; i < 2; ++i)
      #pragma unroll
      for (int rt = 0; rt < 4; ++rt)
        acc2[i][rt] = __builtin_amdgcn_mfma_f32_16x16x32_bf16(afs[i], bfp[rt], acc2[i][rt], 0, 0, 0);
  }
  // store: D row=d(quad*4+reg), col=row(lm)
  #pragma unroll
  for (int i = 0; i < 2; ++i){
    int d0 = (2*w+i)*16 + quad*4;
    #pragma unroll
    for (int rt = 0; rt < 4; ++rt){
      int grow = bp*256 + nt*64 + rt*16 + lm;
      uint2 sp = *(const uint2*)&spa[grow*128 + d0];
      f4 a = acc2[i][rt];
      a.x += b2f((u16)(sp.x & 0xffff)); a.y += b2f((u16)(sp.x >> 16));
      a.z += b2f((u16)(sp.y & 0xffff)); a.w += b2f((u16)(sp.y >> 16));
      uint2 p; p.x = pk(a.x, a.y); p.y = pk(a.z, a.w);
      *(uint2*)&agg[grow*128 + d0] = p;
    }
  }
}

// ---------------- final BN + leaky, in place ----------------
__global__ void k_bnout(float* __restrict__ outp){
  int idx = blockIdx.x*256 + threadIdx.x;
  int flat = idx*4;
  int o = flat & 127;
  float4 v = *(const float4*)(outp + flat);
  v.x = lrelu(fmaf(v.x, g_sb[2][0][o+0], g_sb[2][1][o+0]));
  v.y = lrelu(fmaf(v.y, g_sb[2][0][o+1], g_sb[2][1][o+1]));
  v.z = lrelu(fmaf(v.z, g_sb[2][0][o+2], g_sb[2][1][o+2]));
  v.w = lrelu(fmaf(v.w, g_sb[2][0][o+3], g_sb[2][1][o+3]));
  *(float4*)(outp + flat) = v;
}

extern "C" void kernel_launch(void* const* d_in, const int* in_sizes, int n_in,
                              void* d_out, int out_size, void* d_ws, size_t ws_size,
                              hipStream_t stream) {
  const float* x    = (const float*)d_in[0];
  const float* w1   = (const float*)d_in[1];
  const float* bn1g = (const float*)d_in[2];
  const float* bn1b = (const float*)d_in[3];
  const float* w2   = (const float*)d_in[4];
  const float* bn2g = (const float*)d_in[5];
  const float* bn2b = (const float*)d_in[6];
  const float* mapw = (const float*)d_in[7];
  const float* mapb = (const float*)d_in[8];
  const float* thw  = (const float*)d_in[9];
  const float* thb  = (const float*)d_in[10];
  const float* bnSg = (const float*)d_in[11];
  const float* bnSb = (const float*)d_in[12];
  float* outp = (float*)d_out;

  // ws (64 MB): spa (16M bf16) + agg (16M bf16)
  u16* spa = (u16*)d_ws;
  u16* agg = spa + 16777216;

  // d_out scratch phases: y1hl (bf16 hi/lo pairs, 64 MB exact) -> mapped (fp32) -> out_pre (fp32)
  u16*   y1hl   = (u16*)d_out;
  float* mapped = outp;

  k_zero<<<3, 256, 0, stream>>>();
  k_prepw<<<416, 256, 0, stream>>>(w1, w2, mapw, thw);
  k_conv1<<<2048, 256, 0, stream>>>(x, y1hl);
  k_finalize<<<1, 128, 0, stream>>>(bn1g, bn1b, 0);
  k_conv2<<<2048, 256, 0, stream>>>(y1hl, spa);
  k_finalize<<<1, 128, 0, stream>>>(bn2g, bn2b, 1);
  k_act<<<8192, 256, 0, stream>>>(spa);
  k_gemm128b<<<2048, 256, 0, stream>>>(spa, mapb, mapped, 0, 0);
  k_adjagg<<<2048, 256, 0, stream>>>(mapped, spa, agg);
  k_gemm128b<<<2048, 256, 0, stream>>>(agg, thb, outp, 1, 1);
  k_finalize<<<1, 128, 0, stream>>>(bnSg, bnSb, 2);
  k_bnout<<<16384, 256, 0, stream>>>(outp);
}

// Round 6
// 451.199 us; speedup vs baseline: 4.3006x; 2.7255x over previous
//
#include <hip/hip_runtime.h>

#define SLOPE 0.01f
#define EPSB 1e-5f
#define INV_CNT (1.0f/131072.0f)

typedef unsigned short u16;
typedef unsigned int u32;
typedef __attribute__((ext_vector_type(8))) short s16x8;
typedef __attribute__((ext_vector_type(4))) float f4;

__device__ float g_stats[3][2][128];   // [which][sum|sq][channel]
__device__ float g_sb[3][2][128];      // [which][scale|bias][channel]
__device__ float g_part[2048][256];    // per-block partial stats [block][sum128|sq128]
__device__ u16 g_w1h[3][128][64];      // [k][co][ci] hi
__device__ u16 g_w1l[3][128][64];      // lo
__device__ u16 g_w2h[3][128][128];
__device__ u16 g_w2l[3][128][128];
__device__ u16 g_wmh[128][128];        // [e][d]
__device__ u16 g_wml[128][128];
__device__ u16 g_wqh[128][128];        // theta
__device__ u16 g_wql[128][128];

__device__ __forceinline__ float lrelu(float x){ return x > 0.f ? x : SLOPE*x; }
__device__ __forceinline__ u16 f2b(float f){
  u32 u = __float_as_uint(f);
  return (u16)((u + 0x7fffu + ((u >> 16) & 1u)) >> 16);   // RNE
}
__device__ __forceinline__ float b2f(u16 h){ return __uint_as_float(((u32)h) << 16); }
__device__ __forceinline__ u32 pk(float a, float b){ return (u32)f2b(a) | ((u32)f2b(b) << 16); }
__device__ __forceinline__ u32 pkhl(float f){
  u16 h = f2b(f);
  u16 l = f2b(f - b2f(h));
  return (u32)h | ((u32)l << 16);
}
__device__ __forceinline__ float unhl(u32 v){ return b2f((u16)(v & 0xffff)) + b2f((u16)(v >> 16)); }

// ---------------- zero stats ----------------
__global__ void k_zero(){
  int i = blockIdx.x*256 + threadIdx.x;
  if (i < 768) ((float*)g_stats)[i] = 0.f;
}

// ---------------- reduce per-block partials -> g_stats[which] ----------------
// 16 blocks x 256 threads; block b sums rows [b*128, b*128+128); 16 atomics/address total.
__global__ void k_reduce(int which){
  const float* base = &g_part[blockIdx.x*128][0];
  int j = threadIdx.x;
  float s = 0.f;
  #pragma unroll 4
  for (int r = 0; r < 128; ++r) s += base[r*256 + j];
  atomicAdd(&((float*)g_stats)[which*256 + j], s);
}

// ---------------- prep: fp32 weights -> bf16 hi/lo device globals ----------------
__global__ void k_prepw(const float* __restrict__ w1, const float* __restrict__ w2,
                        const float* __restrict__ mapw, const float* __restrict__ thw){
  int idx = blockIdx.x*256 + threadIdx.x;
  if (idx < 24576){
    int kk = idx >> 13, r = idx & 8191, co = r >> 6, ci = r & 63;
    float v = w1[co*192 + ci*3 + kk];
    u16 h = f2b(v);
    g_w1h[kk][co][ci] = h; g_w1l[kk][co][ci] = f2b(v - b2f(h));
  } else if (idx < 73728){
    int j = idx - 24576;
    int kk = j >> 14, r = j & 16383, co = r >> 7, ci = r & 127;
    float v = w2[co*384 + ci*3 + kk];
    u16 h = f2b(v);
    g_w2h[kk][co][ci] = h; g_w2l[kk][co][ci] = f2b(v - b2f(h));
  } else if (idx < 90112){
    int j = idx - 73728;
    float v = mapw[j];
    u16 h = f2b(v);
    ((u16*)g_wmh)[j] = h; ((u16*)g_wml)[j] = f2b(v - b2f(h));
  } else if (idx < 106496){
    int j = idx - 90112;
    float v = thw[j];
    u16 h = f2b(v);
    ((u16*)g_wqh)[j] = h; ((u16*)g_wql)[j] = f2b(v - b2f(h));
  }
}

// ---------------- finalize BN stats -> scale/bias ----------------
__global__ void k_finalize(const float* __restrict__ g, const float* __restrict__ bta, int which){
  int c = threadIdx.x;   // 128
  float mean = g_stats[which][0][c] * INV_CNT;
  float var  = g_stats[which][1][c] * INV_CNT - mean*mean;
  float sc = g[c] * rsqrtf(var + EPSB);
  g_sb[which][0][c] = sc;
  g_sb[which][1][c] = bta[c] - mean*sc;
}

// ---------------- conv1 MFMA: x[b,t,n,64] -> y1hl[bn][t][co][h|l] pairs, BN1 partials ----------------
// M=co (8 tiles), N=(nn,t) (4 tiles); wave: 2 co-tiles x 4 n-tiles. K=(kk,ci)=192.
__global__ __launch_bounds__(256) void k_conv1(const float* __restrict__ x, u16* __restrict__ y1hl){
  __shared__ __align__(16) u16 a0h[2][34][72];
  __shared__ __align__(16) u16 a0l[2][34][72];
  __shared__ __align__(16) u16 w1s[128][72];
  const int bid = blockIdx.x;
  const int bn0 = bid*2;
  const int b = bn0 >> 8, n = bn0 & 255;
  const int tid = threadIdx.x;
  const int w = tid >> 6, l = tid & 63, quad = l >> 4, lm = l & 15;
  f4 acc[2][4];
  #pragma unroll
  for (int i = 0; i < 2; ++i)
    #pragma unroll
    for (int j = 0; j < 4; ++j) acc[i][j] = (f4)0.f;

  { // stage x -> a0h/a0l (hi/lo bf16), transposed to [t][ci]
    int nn = tid >> 7, rem = tid & 127, t = rem >> 2, ci0 = (rem & 3)*16;
    const float* px = x + ((b*32 + t)*256 + n + nn)*64 + ci0;
    u16 hh[16], ll[16];
    #pragma unroll
    for (int j = 0; j < 4; ++j){
      float4 v = *(const float4*)(px + 4*j);
      float vv[4] = {v.x, v.y, v.z, v.w};
      #pragma unroll
      for (int e = 0; e < 4; ++e){
        u16 h = f2b(vv[e]);
        hh[4*j+e] = h; ll[4*j+e] = f2b(vv[e] - b2f(h));
      }
    }
    *(uint4*)&a0h[nn][t+1][ci0]   = *(uint4*)&hh[0];
    *(uint4*)&a0h[nn][t+1][ci0+8] = *(uint4*)&hh[8];
    *(uint4*)&a0l[nn][t+1][ci0]   = *(uint4*)&ll[0];
    *(uint4*)&a0l[nn][t+1][ci0+8] = *(uint4*)&ll[8];
  }
  // zero pad rows t=0,33 (both nn, both arrays): 4 rows x 36 u32 x 2 arrays = 288
  for (int u = tid; u < 288; u += 256){
    int a = u / 144, rr = u % 144, r = rr / 36, cw = rr % 36;
    u32* base = a ? (u32*)&a0l[r>>1][(r&1)*33][0] : (u32*)&a0h[r>>1][(r&1)*33][0];
    base[cw] = 0u;
  }

  for (int kk = 0; kk < 3; ++kk){
    // pass 0: hi weights, terms Hw*Hx + Hw*Lx
    __syncthreads();
    { int co = tid >> 1, c0 = (tid & 1)*32;
      #pragma unroll
      for (int j = 0; j < 4; ++j)
        *(uint4*)&w1s[co][c0 + 8*j] = *(const uint4*)&g_w1h[kk][co][c0 + 8*j];
    }
    __syncthreads();
    #pragma unroll
    for (int s = 0; s < 2; ++s){
      int ci0 = s*32 + quad*8;
      s16x8 af[2], bh[4], bl[4];
      #pragma unroll
      for (int i = 0; i < 2; ++i) af[i] = *(s16x8*)&w1s[(2*w+i)*16 + lm][ci0];
      #pragma unroll
      for (int nt = 0; nt < 4; ++nt){
        bh[nt] = *(s16x8*)&a0h[nt>>1][(nt&1)*16 + lm + kk][ci0];
        bl[nt] = *(s16x8*)&a0l[nt>>1][(nt&1)*16 + lm + kk][ci0];
      }
      #pragma unroll
      for (int i = 0; i < 2; ++i)
        #pragma unroll
        for (int nt = 0; nt < 4; ++nt){
          acc[i][nt] = __builtin_amdgcn_mfma_f32_16x16x32_bf16(af[i], bh[nt], acc[i][nt], 0, 0, 0);
          acc[i][nt] = __builtin_amdgcn_mfma_f32_16x16x32_bf16(af[i], bl[nt], acc[i][nt], 0, 0, 0);
        }
    }
    // pass 1: lo weights, term Lw*Hx
    __syncthreads();
    { int co = tid >> 1, c0 = (tid & 1)*32;
      #pragma unroll
      for (int j = 0; j < 4; ++j)
        *(uint4*)&w1s[co][c0 + 8*j] = *(const uint4*)&g_w1l[kk][co][c0 + 8*j];
    }
    __syncthreads();
    #pragma unroll
    for (int s = 0; s < 2; ++s){
      int ci0 = s*32 + quad*8;
      s16x8 af[2], bh[4];
      #pragma unroll
      for (int i = 0; i < 2; ++i) af[i] = *(s16x8*)&w1s[(2*w+i)*16 + lm][ci0];
      #pragma unroll
      for (int nt = 0; nt < 4; ++nt) bh[nt] = *(s16x8*)&a0h[nt>>1][(nt&1)*16 + lm + kk][ci0];
      #pragma unroll
      for (int i = 0; i < 2; ++i)
        #pragma unroll
        for (int nt = 0; nt < 4; ++nt)
          acc[i][nt] = __builtin_amdgcn_mfma_f32_16x16x32_bf16(af[i], bh[nt], acc[i][nt], 0, 0, 0);
    }
  }
  // epilogue: D row=co(quad*4+reg), col=t(lm). Store 4 (hi,lo) pairs = uint4.
  #pragma unroll
  for (int i = 0; i < 2; ++i){
    int co0 = (2*w+i)*16 + quad*4;
    float s0=0,s1=0,s2=0,s3=0,q0=0,q1=0,q2=0,q3=0;
    #pragma unroll
    for (int nt = 0; nt < 4; ++nt){
      f4 a = acc[i][nt];
      int nn = nt >> 1, t = (nt & 1)*16 + lm;
      uint4 p;
      p.x = pkhl(a.x); p.y = pkhl(a.y); p.z = pkhl(a.z); p.w = pkhl(a.w);
      *(uint4*)&y1hl[(((bn0+nn)*32 + t)*128 + co0)*2] = p;
      s0+=a.x; s1+=a.y; s2+=a.z; s3+=a.w;
      q0+=a.x*a.x; q1+=a.y*a.y; q2+=a.z*a.z; q3+=a.w*a.w;
    }
    #pragma unroll
    for (int m = 1; m < 16; m <<= 1){
      s0+=__shfl_xor(s0,m); s1+=__shfl_xor(s1,m); s2+=__shfl_xor(s2,m); s3+=__shfl_xor(s3,m);
      q0+=__shfl_xor(q0,m); q1+=__shfl_xor(q1,m); q2+=__shfl_xor(q2,m); q3+=__shfl_xor(q3,m);
    }
    if (lm == 0){
      f4 sv = {s0,s1,s2,s3}, qv = {q0,q1,q2,q3};
      *(f4*)&g_part[bid][co0]       = sv;
      *(f4*)&g_part[bid][128 + co0] = qv;
    }
  }
}

// ---------------- conv2 MFMA: bn1+relu(exact y1) -> spa (permuted, bf16, pre-BN2), BN2 partials ----------------
// M=(nn,t) (4 tiles), N=co (8 tiles); wave: 4 m-tiles x 2 co-tiles. K=(kk,ci)=384.
__global__ __launch_bounds__(256) void k_conv2(const u16* __restrict__ y1hl, u16* __restrict__ spa){
  __shared__ __align__(16) u16 a1s[2][34][136];
  __shared__ __align__(16) u16 w2s[128][136];
  const int bid = blockIdx.x;
  const int bn0 = bid*2;
  const int b = bn0 >> 8, n = bn0 & 255;
  const int tid = threadIdx.x;
  const int w = tid >> 6, l = tid & 63, quad = l >> 4, lm = l & 15;
  f4 acc2[4][2];
  #pragma unroll
  for (int mt = 0; mt < 4; ++mt)
    #pragma unroll
    for (int i = 0; i < 2; ++i) acc2[mt][i] = (f4)0.f;

  { // stage bn1+relu(exact y1) -> a1s
    int nn = tid >> 7, rem = tid & 127, t = rem >> 2, ci0 = (rem & 3)*32;
    const u16* py = y1hl + (((bn0+nn)*32 + t)*128)*2;
    #pragma unroll
    for (int j = 0; j < 4; ++j){
      uint4 va = *(const uint4*)&py[(ci0 + 8*j)*2];
      uint4 vb = *(const uint4*)&py[(ci0 + 8*j + 4)*2];
      u32 vv[8] = {va.x, va.y, va.z, va.w, vb.x, vb.y, vb.z, vb.w};
      u16 oo[8];
      #pragma unroll
      for (int e = 0; e < 8; ++e){
        int ci = ci0 + 8*j + e;
        float f = fmaxf(fmaf(unhl(vv[e]), g_sb[0][0][ci], g_sb[0][1][ci]), 0.f);
        oo[e] = f2b(f);
      }
      *(uint4*)&a1s[nn][t+1][ci0 + 8*j] = *(uint4*)&oo[0];
    }
  }
  // pad rows: 136 u16 = 68 u32 per row, 4 rows
  for (int u = tid; u < 272; u += 256){
    int r = u/68, cw = u%68;
    ((u32*)&a1s[r>>1][(r&1)*33][0])[cw] = 0u;
  }

  for (int kk = 0; kk < 3; ++kk){
    #pragma unroll
    for (int pass = 0; pass < 2; ++pass){
      __syncthreads();
      { int co = tid >> 1, c0 = (tid & 1)*64;
        const u16* src = pass ? &g_w2l[kk][co][0] : &g_w2h[kk][co][0];
        #pragma unroll
        for (int j = 0; j < 8; ++j)
          *(uint4*)&w2s[co][c0 + 8*j] = *(const uint4*)&src[c0 + 8*j];
      }
      __syncthreads();
      #pragma unroll
      for (int s = 0; s < 4; ++s){
        int ci0 = s*32 + quad*8;
        s16x8 ax[4], bw[2];
        #pragma unroll
        for (int mt = 0; mt < 4; ++mt) ax[mt] = *(s16x8*)&a1s[mt>>1][(mt&1)*16 + lm + kk][ci0];
        #pragma unroll
        for (int i = 0; i < 2; ++i) bw[i] = *(s16x8*)&w2s[(2*w+i)*16 + lm][ci0];
        #pragma unroll
        for (int mt = 0; mt < 4; ++mt)
          #pragma unroll
          for (int i = 0; i < 2; ++i)
            acc2[mt][i] = __builtin_amdgcn_mfma_f32_16x16x32_bf16(ax[mt], bw[i], acc2[mt][i], 0, 0, 0);
      }
    }
  }
  // epilogue: D row=t(quad*4+reg), col=co(lm); permuted spa store, partial stats
  #pragma unroll
  for (int i = 0; i < 2; ++i){
    int co = (2*w+i)*16 + lm;
    float s = 0.f, q = 0.f;
    #pragma unroll
    for (int mt = 0; mt < 4; ++mt){
      f4 a = acc2[mt][i];
      int off0 = co*32 + (mt&1)*16 + quad*4;       // off = co*32 + t
      int tp = off0 >> 7, cp = off0 & 127;
      int row = (b*32 + tp)*256 + (n + (mt>>1));
      uint2 p; p.x = pk(a.x, a.y); p.y = pk(a.z, a.w);
      *(uint2*)&spa[row*128 + cp] = p;
      s += a.x + a.y + a.z + a.w;
      q += a.x*a.x + a.y*a.y + a.z*a.z + a.w*a.w;
    }
    s += __shfl_xor(s, 16); s += __shfl_xor(s, 32);
    q += __shfl_xor(q, 16); q += __shfl_xor(q, 32);
    if (l < 16){
      g_part[bid][co]       = s;
      g_part[bid][128 + co] = q;
    }
  }
}

// ---------------- in-place BN2 + relu on spa ----------------
__global__ void k_act(u16* __restrict__ spa){
  int idx = blockIdx.x*256 + threadIdx.x;
  int flat = idx*8;
  int cp0 = flat & 127;
  int row = flat >> 7;
  int bpp = row >> 8;
  int tp = bpp & 31;
  int c = (tp*128 + cp0) >> 5;
  float sc = g_sb[1][0][c], bi = g_sb[1][1][c];
  uint4 v = *(uint4*)(spa + flat);
  u16 h[8]; *(uint4*)&h[0] = v;
  u16 o[8];
  #pragma unroll
  for (int i = 0; i < 8; ++i) o[i] = f2b(fmaxf(fmaf(b2f(h[i]), sc, bi), 0.f));
  *(uint4*)(spa + flat) = *(uint4*)&o[0];
}

// ---------------- gemm128 MFMA: out[r][e] = sum_d A[r][d]*W[e][d] + b[e], W two-pass hi/lo ----------------
// M=e (8 tiles), N=rows (4 tiles); wave: 2 e-tiles x 4 row-tiles. K=128.
__global__ __launch_bounds__(256) void k_gemm128b(const u16* __restrict__ A,
                                                  const float* __restrict__ bvec,
                                                  float* __restrict__ outp,
                                                  int wsel, int do_stats){
  __shared__ __align__(16) u16 As[64][136];
  __shared__ __align__(16) u16 Ws[128][136];
  const u16* Wh = wsel ? &g_wqh[0][0] : &g_wmh[0][0];
  const u16* Wl = wsel ? &g_wql[0][0] : &g_wml[0][0];
  const int bid = blockIdx.x;
  const int rowbase = bid * 64;
  const int tid = threadIdx.x;
  const int w = tid >> 6, l = tid & 63, quad = l >> 4, lm = l & 15;
  f4 acc[2][4];
  #pragma unroll
  for (int i = 0; i < 2; ++i)
    #pragma unroll
    for (int rt = 0; rt < 4; ++rt) acc[i][rt] = (f4)0.f;

  { int r = tid >> 2, c0 = (tid & 3)*32;
    #pragma unroll
    for (int j = 0; j < 4; ++j)
      *(uint4*)&As[r][c0 + 8*j] = *(const uint4*)&A[(rowbase + r)*128 + c0 + 8*j];
  }
  #pragma unroll
  for (int pass = 0; pass < 2; ++pass){
    if (pass) __syncthreads();
    { int e = tid >> 1, c0 = (tid & 1)*64;
      const u16* src = (pass ? Wl : Wh) + e*128;
      #pragma unroll
      for (int j = 0; j < 8; ++j)
        *(uint4*)&Ws[e][c0 + 8*j] = *(const uint4*)&src[c0 + 8*j];
    }
    __syncthreads();
    #pragma unroll
    for (int s = 0; s < 4; ++s){
      int k0 = s*32 + quad*8;
      s16x8 aw[2], ba[4];
      #pragma unroll
      for (int i = 0; i < 2; ++i) aw[i] = *(s16x8*)&Ws[(2*w+i)*16 + lm][k0];
      #pragma unroll
      for (int rt = 0; rt < 4; ++rt) ba[rt] = *(s16x8*)&As[rt*16 + lm][k0];
      #pragma unroll
      for (int i = 0; i < 2; ++i)
        #pragma unroll
        for (int rt = 0; rt < 4; ++rt)
          acc[i][rt] = __builtin_amdgcn_mfma_f32_16x16x32_bf16(aw[i], ba[rt], acc[i][rt], 0, 0, 0);
    }
    if (!pass) __syncthreads();   // all reads done before Ws restage
  }
  // epilogue: D row=e(quad*4+reg), col=row(lm) -> float4 stores along e
  #pragma unroll
  for (int i = 0; i < 2; ++i){
    int e0 = (2*w+i)*16 + quad*4;
    f4 bv = *(const f4*)&bvec[e0];
    f4 sv = (f4)0.f, qv = (f4)0.f;
    #pragma unroll
    for (int rt = 0; rt < 4; ++rt){
      int row = rowbase + rt*16 + lm;
      f4 o = acc[i][rt] + bv;
      *(f4*)&outp[row*128 + e0] = o;
      sv += o; qv += o*o;
    }
    if (do_stats){
      #pragma unroll
      for (int m = 1; m < 16; m <<= 1){
        sv.x+=__shfl_xor(sv.x,m); sv.y+=__shfl_xor(sv.y,m); sv.z+=__shfl_xor(sv.z,m); sv.w+=__shfl_xor(sv.w,m);
        qv.x+=__shfl_xor(qv.x,m); qv.y+=__shfl_xor(qv.y,m); qv.z+=__shfl_xor(qv.z,m); qv.w+=__shfl_xor(qv.w,m);
      }
      if (lm == 0){
        *(f4*)&g_part[bid][e0]       = sv;
        *(f4*)&g_part[bid][128 + e0] = qv;
      }
    }
  }
}

// ---------------- fused adj+agg MFMA, mapped staged hi/lo ----------------
__global__ __launch_bounds__(256) void k_adjagg(const float* __restrict__ mapped,
                                                const u16* __restrict__ spa,
                                                u16* __restrict__ agg){
  __shared__ __align__(16) char smem[44032];
  u16 (*mbh)[40]   = (u16(*)[40])(smem);
  u16 (*mbl)[40]   = (u16(*)[40])(smem + 20480);
  u16 (*Ps)[264]   = (u16(*)[264])(smem);
  u16 (*spasT)[40] = (u16(*)[40])(smem + 33792);
  const int bp = blockIdx.x >> 2;
  const int nt = blockIdx.x & 3;
  const int tid = threadIdx.x;
  const int w = tid >> 6, l = tid & 63, quad = l >> 4, lm = l & 15;

  // ---- phase 1: S rows (wave w -> row-tile w) x all 256 cols, hi/lo 3-term ----
  f4 sacc[16];
  #pragma unroll
  for (int ct = 0; ct < 16; ++ct) sacc[ct] = (f4)0.f;

  for (int dc = 0; dc < 4; ++dc){
    __syncthreads();
    { int m = tid;
      const float* pm = mapped + (bp*256 + m)*128 + dc*32;
      u16 hh[32], ll[32];
      #pragma unroll
      for (int j = 0; j < 8; ++j){
        float4 v = *(const float4*)(pm + 4*j);
        float vv[4] = {v.x, v.y, v.z, v.w};
        #pragma unroll
        for (int e = 0; e < 4; ++e){
          u16 h = f2b(vv[e]);
          hh[4*j+e] = h; ll[4*j+e] = f2b(vv[e] - b2f(h));
        }
      }
      #pragma unroll
      for (int j = 0; j < 4; ++j){
        *(uint4*)&mbh[m][8*j] = *(uint4*)&hh[8*j];
        *(uint4*)&mbl[m][8*j] = *(uint4*)&ll[8*j];
      }
    }
    __syncthreads();
    s16x8 amh = *(s16x8*)&mbh[nt*64 + w*16 + lm][quad*8];
    s16x8 aml = *(s16x8*)&mbl[nt*64 + w*16 + lm][quad*8];
    #pragma unroll
    for (int ct = 0; ct < 16; ++ct){
      s16x8 bmh = *(s16x8*)&mbh[ct*16 + lm][quad*8];
      s16x8 bml = *(s16x8*)&mbl[ct*16 + lm][quad*8];
      sacc[ct] = __builtin_amdgcn_mfma_f32_16x16x32_bf16(amh, bmh, sacc[ct], 0, 0, 0);
      sacc[ct] = __builtin_amdgcn_mfma_f32_16x16x32_bf16(amh, bml, sacc[ct], 0, 0, 0);
      sacc[ct] = __builtin_amdgcn_mfma_f32_16x16x32_bf16(aml, bmh, sacc[ct], 0, 0, 0);
    }
  }
  __syncthreads();   // all mbuf reads done; Ps may now overlay

  // ---- softmax (regs only) -> Ps[row][m] bf16 ----
  #pragma unroll
  for (int r = 0; r < 4; ++r){
    int rowg = nt*64 + w*16 + quad*4 + r;
    float v[16]; float mx = -3.0e38f;
    #pragma unroll
    for (int ct = 0; ct < 16; ++ct){
      float t = sacc[ct][r];
      if (ct*16 + lm == rowg) t -= 1e8f;
      t = lrelu(t);
      v[ct] = t; mx = fmaxf(mx, t);
    }
    #pragma unroll
    for (int m = 1; m < 16; m <<= 1) mx = fmaxf(mx, __shfl_xor(mx, m));
    float sum = 0.f;
    #pragma unroll
    for (int ct = 0; ct < 16; ++ct){ float e = __expf(v[ct] - mx); v[ct] = e; sum += e; }
    #pragma unroll
    for (int m = 1; m < 16; m <<= 1) sum += __shfl_xor(sum, m);
    float inv = 1.0f / sum;
    #pragma unroll
    for (int ct = 0; ct < 16; ++ct)
      Ps[w*16 + quad*4 + r][ct*16 + lm] = f2b(v[ct] * inv);
  }

  // ---- phase 2: agg = P @ spa (+ spa for +I). M=d (2 d-tiles/wave), N=rows (4 tiles). ----
  f4 acc2[2][4];
  #pragma unroll
  for (int i = 0; i < 2; ++i)
    #pragma unroll
    for (int rt = 0; rt < 4; ++rt) acc2[i][rt] = (f4)0.f;

  for (int mc = 0; mc < 8; ++mc){
    __syncthreads();
    { int ml = tid >> 3, d0 = (tid & 7)*16;     // transpose-stage spa chunk
      const u16* ps = spa + (bp*256 + mc*32 + ml)*128 + d0;
      u16 h[16];
      *(uint4*)&h[0] = *(const uint4*)ps;
      *(uint4*)&h[8] = *(const uint4*)(ps + 8);
      #pragma unroll
      for (int j = 0; j < 16; ++j) spasT[d0 + j][ml] = h[j];
    }
    __syncthreads();
    s16x8 afs[2], bfp[4];
    #pragma unroll
    for (int i = 0; i < 2; ++i) afs[i] = *(s16x8*)&spasT[(2*w+i)*16 + lm][quad*8];
    #pragma unroll
    for (int rt = 0; rt < 4; ++rt) bfp[rt] = *(s16x8*)&Ps[rt*16 + lm][mc*32 + quad*8];
    #pragma unroll
    for (int i = 0; i < 2; ++i)
      #pragma unroll
      for (int rt = 0; rt < 4; ++rt)
        acc2[i][rt] = __builtin_amdgcn_mfma_f32_16x16x32_bf16(afs[i], bfp[rt], acc2[i][rt], 0, 0, 0);
  }
  // store: D row=d(quad*4+reg), col=row(lm)
  #pragma unroll
  for (int i = 0; i < 2; ++i){
    int d0 = (2*w+i)*16 + quad*4;
    #pragma unroll
    for (int rt = 0; rt < 4; ++rt){
      int grow = bp*256 + nt*64 + rt*16 + lm;
      uint2 sp = *(const uint2*)&spa[grow*128 + d0];
      f4 a = acc2[i][rt];
      a.x += b2f((u16)(sp.x & 0xffff)); a.y += b2f((u16)(sp.x >> 16));
      a.z += b2f((u16)(sp.y & 0xffff)); a.w += b2f((u16)(sp.y >> 16));
      uint2 p; p.x = pk(a.x, a.y); p.y = pk(a.z, a.w);
      *(uint2*)&agg[grow*128 + d0] = p;
    }
  }
}

// ---------------- final BN + leaky, in place ----------------
__global__ void k_bnout(float* __restrict__ outp){
  int idx = blockIdx.x*256 + threadIdx.x;
  int flat = idx*4;
  int o = flat & 127;
  float4 v = *(const float4*)(outp + flat);
  v.x = lrelu(fmaf(v.x, g_sb[2][0][o+0], g_sb[2][1][o+0]));
  v.y = lrelu(fmaf(v.y, g_sb[2][0][o+1], g_sb[2][1][o+1]));
  v.z = lrelu(fmaf(v.z, g_sb[2][0][o+2], g_sb[2][1][o+2]));
  v.w = lrelu(fmaf(v.w, g_sb[2][0][o+3], g_sb[2][1][o+3]));
  *(float4*)(outp + flat) = v;
}

extern "C" void kernel_launch(void* const* d_in, const int* in_sizes, int n_in,
                              void* d_out, int out_size, void* d_ws, size_t ws_size,
                              hipStream_t stream) {
  const float* x    = (const float*)d_in[0];
  const float* w1   = (const float*)d_in[1];
  const float* bn1g = (const float*)d_in[2];
  const float* bn1b = (const float*)d_in[3];
  const float* w2   = (const float*)d_in[4];
  const float* bn2g = (const float*)d_in[5];
  const float* bn2b = (const float*)d_in[6];
  const float* mapw = (const float*)d_in[7];
  const float* mapb = (const float*)d_in[8];
  const float* thw  = (const float*)d_in[9];
  const float* thb  = (const float*)d_in[10];
  const float* bnSg = (const float*)d_in[11];
  const float* bnSb = (const float*)d_in[12];
  float* outp = (float*)d_out;

  // ws (64 MB): spa (16M bf16) + agg (16M bf16)
  u16* spa = (u16*)d_ws;
  u16* agg = spa + 16777216;

  // d_out scratch phases: y1hl (bf16 hi/lo pairs, 64 MB exact) -> mapped (fp32) -> out_pre (fp32)
  u16*   y1hl   = (u16*)d_out;
  float* mapped = outp;

  k_zero<<<3, 256, 0, stream>>>();
  k_prepw<<<416, 256, 0, stream>>>(w1, w2, mapw, thw);
  k_conv1<<<2048, 256, 0, stream>>>(x, y1hl);
  k_reduce<<<16, 256, 0, stream>>>(0);
  k_finalize<<<1, 128, 0, stream>>>(bn1g, bn1b, 0);
  k_conv2<<<2048, 256, 0, stream>>>(y1hl, spa);
  k_reduce<<<16, 256, 0, stream>>>(1);
  k_finalize<<<1, 128, 0, stream>>>(bn2g, bn2b, 1);
  k_act<<<8192, 256, 0, stream>>>(spa);
  k_gemm128b<<<2048, 256, 0, stream>>>(spa, mapb, mapped, 0, 0);
  k_adjagg<<<2048, 256, 0, stream>>>(mapped, spa, agg);
  k_gemm128b<<<2048, 256, 0, stream>>>(agg, thb, outp, 1, 1);
  k_reduce<<<16, 256, 0, stream>>>(2);
  k_finalize<<<1, 128, 0, stream>>>(bnSg, bnSb, 2);
  k_bnout<<<16384, 256, 0, stream>>>(outp);
}